// Round 3
// baseline (121.596 us; speedup 1.0000x reference)
//
#include <hip/hip_runtime.h>

// WaveletNet: P/U filters are length-1, so the "circular convolution" is a
// scalar multiply. Pure elementwise lifting recurrence over (even, odd) pairs.
// x: (B, L) fp32 -> z: (B, 2, L/2) fp32, plus scalar log_det=0 appended.
//
// R2: native ext_vector_type(4) for nontemporal builtins (HIP_vector_type is
// a class and is rejected). 4 pairs/thread -> 16 B/lane loads AND stores.

#define BB 256
#define LL 65536
#define HH (LL / 2)        // 32768 pairs per row
#define PAIRS_PER_THREAD 4

typedef float vfloat4 __attribute__((ext_vector_type(4)));

__device__ __forceinline__ void lift4(float& e, float& o,
                                      const float p0, const float p1,
                                      const float p2, const float p3,
                                      const float u0, const float u1,
                                      const float u2, const float u3) {
    float d, a;
    d = o - p0 * e; a = e + u0 * d; e = a; o = d;
    d = o - p1 * e; a = e + u1 * d; e = a; o = d;
    d = o - p2 * e; a = e + u2 * d; e = a; o = d;
    d = o - p3 * e; a = e + u3 * d; e = a; o = d;
}

__global__ __launch_bounds__(256) void wavelet_lift_kernel(
    const vfloat4* __restrict__ x4,  // B*L/4 vec4s: (e,o,e,o)
    const float* __restrict__ P,     // 4 coeffs
    const float* __restrict__ U,     // 4 coeffs
    float* __restrict__ out)         // B*2*H floats, then log_det at [B*L]
{
    const int tid = blockIdx.x * blockDim.x + threadIdx.x;
    // total threads = B*H/4 = 2,097,152; each handles 4 consecutive pairs

    const float p0 = P[0], p1 = P[1], p2 = P[2], p3 = P[3];
    const float u0 = U[0], u1 = U[1], u2 = U[2], u3 = U[3];

    const int b = tid >> 13;              // tid / (H/4)
    const int i = (tid & 8191) << 2;      // starting pair index within row

    // input vec4 index for pair i of row b: (b*L + 2*i)/4
    const long base = (long)b * (LL / 4) + (i >> 1);
    const vfloat4 v0 = __builtin_nontemporal_load(&x4[base]);
    const vfloat4 v1 = __builtin_nontemporal_load(&x4[base + 1]);

    float e0 = v0.x, o0 = v0.y, e1 = v0.z, o1 = v0.w;
    float e2 = v1.x, o2 = v1.y, e3 = v1.z, o3 = v1.w;

    lift4(e0, o0, p0, p1, p2, p3, u0, u1, u2, u3);
    lift4(e1, o1, p0, p1, p2, p3, u0, u1, u2, u3);
    lift4(e2, o2, p0, p1, p2, p3, u0, u1, u2, u3);
    lift4(e3, o3, p0, p1, p2, p3, u0, u1, u2, u3);

    // output: z[b][0][i..i+3] and z[b][1][i..i+3]
    vfloat4* rowE = (vfloat4*)(out + (size_t)b * (2 * HH) + i);
    vfloat4* rowO = (vfloat4*)((float*)rowE + HH);
    vfloat4 ve = {e0, e1, e2, e3};
    vfloat4 vo = {o0, o1, o2, o3};
    __builtin_nontemporal_store(ve, rowE);
    __builtin_nontemporal_store(vo, rowO);

    if (tid == 0) {
        out[(size_t)BB * LL] = 0.0f;      // log_det
    }
}

extern "C" void kernel_launch(void* const* d_in, const int* in_sizes, int n_in,
                              void* d_out, int out_size, void* d_ws, size_t ws_size,
                              hipStream_t stream) {
    const vfloat4* x4 = (const vfloat4*)d_in[0];
    const float* P = (const float*)d_in[1];
    const float* U = (const float*)d_in[2];
    float* out = (float*)d_out;

    const int total_threads = BB * HH / PAIRS_PER_THREAD;  // 2,097,152
    const int block = 256;
    const int grid = total_threads / block;                // 8192

    wavelet_lift_kernel<<<grid, block, 0, stream>>>(x4, P, U, out);
}

// Round 4
// 114.561 us; speedup vs baseline: 1.0614x; 1.0614x over previous
//
#include <hip/hip_runtime.h>

// WaveletNet: P/U filters are length-1, so the "circular convolution" is a
// scalar multiply. Pure elementwise lifting recurrence over (even, odd) pairs.
// x: (B, L) fp32 -> z: (B, 2, L/2) fp32, plus scalar log_det=0 appended.
//
// R4: drop nontemporal hints (input is L2/L3-resident from the harness
// restore copy; NT forgoes those hits). Keep float4 loads/stores, 4 pairs/thread.

#define BB 256
#define LL 65536
#define HH (LL / 2)        // 32768 pairs per row
#define PAIRS_PER_THREAD 4

typedef float vfloat4 __attribute__((ext_vector_type(4)));

__device__ __forceinline__ void lift4(float& e, float& o,
                                      const float p0, const float p1,
                                      const float p2, const float p3,
                                      const float u0, const float u1,
                                      const float u2, const float u3) {
    float d, a;
    d = o - p0 * e; a = e + u0 * d; e = a; o = d;
    d = o - p1 * e; a = e + u1 * d; e = a; o = d;
    d = o - p2 * e; a = e + u2 * d; e = a; o = d;
    d = o - p3 * e; a = e + u3 * d; e = a; o = d;
}

__global__ __launch_bounds__(256) void wavelet_lift_kernel(
    const vfloat4* __restrict__ x4,  // B*L/4 vec4s: (e,o,e,o)
    const float* __restrict__ P,     // 4 coeffs
    const float* __restrict__ U,     // 4 coeffs
    float* __restrict__ out)         // B*2*H floats, then log_det at [B*L]
{
    const int tid = blockIdx.x * blockDim.x + threadIdx.x;
    // total threads = B*H/4 = 2,097,152; each handles 4 consecutive pairs

    const float p0 = P[0], p1 = P[1], p2 = P[2], p3 = P[3];
    const float u0 = U[0], u1 = U[1], u2 = U[2], u3 = U[3];

    const int b = tid >> 13;              // tid / (H/4)
    const int i = (tid & 8191) << 2;      // starting pair index within row

    // input vec4 index for pair i of row b: (b*L + 2*i)/4
    const long base = (long)b * (LL / 4) + (i >> 1);
    const vfloat4 v0 = x4[base];
    const vfloat4 v1 = x4[base + 1];

    float e0 = v0.x, o0 = v0.y, e1 = v0.z, o1 = v0.w;
    float e2 = v1.x, o2 = v1.y, e3 = v1.z, o3 = v1.w;

    lift4(e0, o0, p0, p1, p2, p3, u0, u1, u2, u3);
    lift4(e1, o1, p0, p1, p2, p3, u0, u1, u2, u3);
    lift4(e2, o2, p0, p1, p2, p3, u0, u1, u2, u3);
    lift4(e3, o3, p0, p1, p2, p3, u0, u1, u2, u3);

    // output: z[b][0][i..i+3] and z[b][1][i..i+3]
    vfloat4* rowE = (vfloat4*)(out + (size_t)b * (2 * HH) + i);
    vfloat4* rowO = (vfloat4*)((float*)rowE + HH);
    vfloat4 ve = {e0, e1, e2, e3};
    vfloat4 vo = {o0, o1, o2, o3};
    *rowE = ve;
    *rowO = vo;

    if (tid == 0) {
        out[(size_t)BB * LL] = 0.0f;      // log_det
    }
}

extern "C" void kernel_launch(void* const* d_in, const int* in_sizes, int n_in,
                              void* d_out, int out_size, void* d_ws, size_t ws_size,
                              hipStream_t stream) {
    const vfloat4* x4 = (const vfloat4*)d_in[0];
    const float* P = (const float*)d_in[1];
    const float* U = (const float*)d_in[2];
    float* out = (float*)d_out;

    const int total_threads = BB * HH / PAIRS_PER_THREAD;  // 2,097,152
    const int block = 256;
    const int grid = total_threads / block;                // 8192

    wavelet_lift_kernel<<<grid, block, 0, stream>>>(x4, P, U, out);
}